// Round 14
// baseline (238.415 us; speedup 1.0000x reference)
//
#include <hip/hip_runtime.h>

// Problem constants (match reference setup_inputs)
#define BATCH    2
#define NPART    4096
#define NTHREADS 512
#define ILANES   2                    // lane slots in i-dim
#define IPL      4                    // i per lane (two v2f chains)
#define IBLK     (ILANES * IPL)       // 8 i per block
#define JCH      (NTHREADS / ILANES)  // 256 j-chunks per block
#define JLEN     (NPART / JCH)        // 16 j per chunk
#define NIB      (NPART / IBLK)       // 512 i-blocks per batch
#define RSTRIDE  25                   // 24 partials + 1 pad (odd -> bank spread)

typedef float v2f __attribute__((ext_vector_type(2)));

// One (j, 2-i) interaction; v2f packs two i's. MASKED handles i==j (r2==0).
template <bool MASKED>
__device__ inline void lj_body(float jx, float jy, float jz,
                               v2f qx, v2f qy, v2f qz,
                               v2f& fx, v2f& fy, v2f& fz) {
    const v2f dx = qx - (v2f)jx;
    const v2f dy = qy - (v2f)jy;
    const v2f dz = qz - (v2f)jz;
    v2f r2 = dx * dx;
    r2 = __builtin_elementwise_fma(dy, dy, r2);
    r2 = __builtin_elementwise_fma(dz, dz, r2);
    v2f inv;
    if (MASKED) {   // r2==0.0f exactly <=> i==j (reference's mask semantics)
        inv.x = (r2.x > 0.0f) ? __builtin_amdgcn_rcpf(r2.x) : 0.0f;
        inv.y = (r2.y > 0.0f) ? __builtin_amdgcn_rcpf(r2.y) : 0.0f;
    } else {
        inv.x = __builtin_amdgcn_rcpf(r2.x);
        inv.y = __builtin_amdgcn_rcpf(r2.y);
    }
    const v2f inv2 = inv * inv;
    const v2f s6 = inv2 * inv;                                      // sigma = 1
    const v2f c1 = __builtin_elementwise_fma((v2f)48.0f, s6, (v2f)(-24.0f));
    const v2f coeff = (inv * s6) * c1;     // 24*inv*s6*(2*s6-1)
    fx = __builtin_elementwise_fma(coeff, dx, fx);
    fy = __builtin_elementwise_fma(coeff, dy, fy);
    fz = __builtin_elementwise_fma(coeff, dz, fz);
}

// This lane's 16-j chunk: 12 float4 loads; each j feeds both v2f chains (8 pairs).
template <bool MASKED>
__device__ inline void chunk_loop(const float4* __restrict__ jq4,
                                  const v2f* qx, const v2f* qy, const v2f* qz,
                                  v2f* fx, v2f* fy, v2f* fz) {
    #pragma unroll
    for (int it = 0; it < JLEN / 4; ++it) {
        const float4 A = jq4[3 * it + 0];   // x0 y0 z0 x1
        const float4 B = jq4[3 * it + 1];   // y1 z1 x2 y2
        const float4 C = jq4[3 * it + 2];   // z2 x3 y3 z3
        const float jxs[4] = {A.x, A.w, B.z, C.y};
        const float jys[4] = {A.y, B.x, B.w, C.z};
        const float jzs[4] = {A.z, B.y, C.x, C.w};
        #pragma unroll
        for (int u = 0; u < 4; ++u) {
            #pragma unroll
            for (int cc = 0; cc < 2; ++cc) {
                lj_body<MASKED>(jxs[u], jys[u], jzs[u],
                                qx[cc], qy[cc], qz[cc], fx[cc], fy[cc], fz[cc]);
            }
        }
    }
}

// Fully fused single dispatch. Block owns 8 i's (4 per lane: i = ib*8+il+2cc+4h)
// x all 4096 j (256 chunks of 16 across lanes); LDS tree reduction.
// 1024 blocks x 512 thr = 4 blocks/CU, 8 waves/SIMD. Only wave (ib>>6) can see
// the diagonal -> 7/8 waves run maskless bodies.
__global__ __launch_bounds__(NTHREADS, 8) void lj_fused(
        const float* __restrict__ q, const float* __restrict__ p,
        const float* __restrict__ m, float* __restrict__ dq,
        float* __restrict__ dp) {
    __shared__ float red[JCH * RSTRIDE];   // 25.6 KB
    __shared__ float red2[24 * 16];        // stage-1 partials

    const int ib = blockIdx.x;
    const int b  = blockIdx.y;
    const int t  = threadIdx.x;
    const int il = t & 1;
    const int jc = t >> 1;                 // 0..255

    const float* qb = q + (size_t)b * NPART * 3;

    v2f qx[2], qy[2], qz[2], fx[2], fy[2], fz[2];
    #pragma unroll
    for (int cc = 0; cc < 2; ++cc) {
        const int iA = ib * IBLK + il + 2 * cc;   // h = 0
        const int iB = iA + 4;                    // h = 1
        qx[cc] = (v2f){qb[iA * 3 + 0], qb[iB * 3 + 0]};
        qy[cc] = (v2f){qb[iA * 3 + 1], qb[iB * 3 + 1]};
        qz[cc] = (v2f){qb[iA * 3 + 2], qb[iB * 3 + 2]};
        fx[cc] = (v2f)0.0f; fy[cc] = (v2f)0.0f; fz[cc] = (v2f)0.0f;
    }

    const float4* jq4 = (const float4*)(qb + (size_t)jc * JLEN * 3);

    // Diagonal chunk = ib>>1; it lives in wave (ib>>6).
    if ((t >> 6) == (ib >> 6)) {
        chunk_loop<true >(jq4, qx, qy, qz, fx, fy, fz);
    } else {
        chunk_loop<false>(jq4, qx, qy, qz, fx, fy, fz);
    }

    // 12 partials/thread: slot = comp*4 + cc*2 + h; addr = jc*25 + slot*2 + il
    {
        float* r = &red[jc * RSTRIDE + il];
        r[0]  = fx[0].x;  r[2]  = fx[0].y;  r[4]  = fx[1].x;  r[6]  = fx[1].y;
        r[8]  = fy[0].x;  r[10] = fy[0].y;  r[12] = fy[1].x;  r[14] = fy[1].y;
        r[16] = fz[0].x;  r[18] = fz[0].y;  r[20] = fz[1].x;  r[22] = fz[1].y;
    }
    __syncthreads();

    // Stage 1: 384 threads; output o = comp*8 + (il + 2cc + 4h), group g of 16 chunks.
    if (t < 384) {
        const int o  = t >> 4;         // 0..23
        const int g  = t & 15;         // 0..15
        const int comp = o >> 3;
        const int rr   = o & 7;
        const int il2  = rr & 1;
        const int cc2  = (rr >> 1) & 1;
        const int h2   = rr >> 2;
        const int slot = comp * 4 + cc2 * 2 + h2;
        float s = 0.0f;
        #pragma unroll
        for (int qq = 0; qq < 16; ++qq) {
            s += red[(g * 16 + qq) * RSTRIDE + slot * 2 + il2];
        }
        red2[o * 16 + g] = s;
    }
    __syncthreads();

    // Stage 2: 24 threads -> one (comp, i-in-block) each; fuse dq = p/m.
    if (t < 24) {
        float s = 0.0f;
        #pragma unroll
        for (int g = 0; g < 16; ++g) s += red2[t * 16 + g];
        const int comp = t >> 3;
        const int ii   = t & 7;        // il + 2cc + 4h
        const size_t gi = (size_t)b * NPART + ib * IBLK + ii;
        dp[gi * 3 + comp] = s;
        dq[gi * 3 + comp] = p[gi * 3 + comp] / m[gi];   // exact IEEE div
    }
}

extern "C" void kernel_launch(void* const* d_in, const int* in_sizes, int n_in,
                              void* d_out, int out_size, void* d_ws, size_t ws_size,
                              hipStream_t stream) {
    const float* q = (const float*)d_in[0];
    const float* p = (const float*)d_in[1];
    const float* m = (const float*)d_in[2];
    // d_in[3] = t, unused by the reference outputs

    const int n_elem = BATCH * NPART * 3;   // 24576 per output tensor
    float* dq_out = (float*)d_out;          // first output: dq
    float* dp_out = (float*)d_out + n_elem; // second output: dp

    dim3 grid(NIB, BATCH);                  // 1024 blocks x 512 threads
    lj_fused<<<grid, NTHREADS, 0, stream>>>(q, p, m, dq_out, dp_out);
}

// Round 15
// 209.072 us; speedup vs baseline: 1.1403x; 1.1403x over previous
//
#include <hip/hip_runtime.h>

// Problem constants (match reference setup_inputs)
#define BATCH    2
#define NPART    4096
#define NTHREADS 512
#define ILANES   2                    // lane slots in i-dim
#define IPL      4                    // i per lane (two v2f chains)
#define IBLK     (ILANES * IPL)       // 8 i per block
#define JCH      (NTHREADS / ILANES)  // 256 j-chunks per block
#define JLEN     (NPART / JCH)        // 16 j per chunk
#define NIB      (NPART / IBLK)       // 512 i-blocks per batch
#define RSTRIDE  25                   // 24 partials + 1 pad

typedef float v2f __attribute__((ext_vector_type(2)));

// One (j, 2-i) interaction; v2f packs two i's. MASKED handles i==j (r2==0).
template <bool MASKED>
__device__ inline void lj_pair(float jx, float jy, float jz,
                               v2f qx, v2f qy, v2f qz,
                               v2f& fx, v2f& fy, v2f& fz) {
    const v2f dx = qx - (v2f)jx;
    const v2f dy = qy - (v2f)jy;
    const v2f dz = qz - (v2f)jz;
    v2f r2 = dx * dx;
    r2 = __builtin_elementwise_fma(dy, dy, r2);
    r2 = __builtin_elementwise_fma(dz, dz, r2);
    v2f inv;
    if (MASKED) {   // r2==0.0f exactly <=> i==j (reference's mask semantics)
        inv.x = (r2.x > 0.0f) ? __builtin_amdgcn_rcpf(r2.x) : 0.0f;
        inv.y = (r2.y > 0.0f) ? __builtin_amdgcn_rcpf(r2.y) : 0.0f;
    } else {
        inv.x = __builtin_amdgcn_rcpf(r2.x);
        inv.y = __builtin_amdgcn_rcpf(r2.y);
    }
    const v2f inv2 = inv * inv;
    const v2f s6 = inv2 * inv;                                      // sigma = 1
    const v2f c1 = __builtin_elementwise_fma((v2f)48.0f, s6, (v2f)(-24.0f));
    const v2f coeff = (inv * s6) * c1;     // 24*inv*s6*(2*s6-1)
    fx = __builtin_elementwise_fma(coeff, dx, fx);
    fy = __builtin_elementwise_fma(coeff, dy, fy);
    fz = __builtin_elementwise_fma(coeff, dz, fz);
}

// One j feeding both v2f chains (4 pairs) -- no staging arrays, low reg pressure.
template <bool MASKED>
__device__ inline void lj_j(float jx, float jy, float jz,
                            const v2f* qx, const v2f* qy, const v2f* qz,
                            v2f* fx, v2f* fy, v2f* fz) {
    lj_pair<MASKED>(jx, jy, jz, qx[0], qy[0], qz[0], fx[0], fy[0], fz[0]);
    lj_pair<MASKED>(jx, jy, jz, qx[1], qy[1], qz[1], fx[1], fy[1], fz[1]);
}

// This lane's 16-j chunk: 12 float4 loads consumed in place.
template <bool MASKED>
__device__ inline void chunk_loop(const float4* __restrict__ jq4,
                                  const v2f* qx, const v2f* qy, const v2f* qz,
                                  v2f* fx, v2f* fy, v2f* fz) {
    #pragma unroll
    for (int it = 0; it < JLEN / 4; ++it) {
        const float4 A = jq4[3 * it + 0];   // x0 y0 z0 x1
        const float4 B = jq4[3 * it + 1];   // y1 z1 x2 y2
        const float4 C = jq4[3 * it + 2];   // z2 x3 y3 z3
        lj_j<MASKED>(A.x, A.y, A.z, qx, qy, qz, fx, fy, fz);
        lj_j<MASKED>(A.w, B.x, B.y, qx, qy, qz, fx, fy, fz);
        lj_j<MASKED>(B.z, B.w, C.x, qx, qy, qz, fx, fy, fz);
        lj_j<MASKED>(C.y, C.z, C.w, qx, qy, qz, fx, fy, fz);
    }
}

// Fully fused single dispatch. Block owns 8 i's (i = ib*8 + il + 2cc + 4h)
// x all 4096 j (256 chunks of 16 across lanes); two-stage LDS reduction.
// launch_bounds(512,4): VGPR cap 128 -> no spill (R14's failure), 4 waves/SIMD.
// Only wave (ib>>6) can see the diagonal -> 7/8 waves run maskless bodies.
__global__ __launch_bounds__(NTHREADS, 4) void lj_fused(
        const float* __restrict__ q, const float* __restrict__ p,
        const float* __restrict__ m, float* __restrict__ dq,
        float* __restrict__ dp) {
    __shared__ float red[JCH * RSTRIDE];   // 25.6 KB
    __shared__ float red2[24 * 16];        // stage-1 partials

    const int ib = blockIdx.x;
    const int b  = blockIdx.y;
    const int t  = threadIdx.x;
    const int il = t & 1;
    const int jc = t >> 1;                 // 0..255

    const float* qb = q + (size_t)b * NPART * 3;

    v2f qx[2], qy[2], qz[2], fx[2], fy[2], fz[2];
    #pragma unroll
    for (int cc = 0; cc < 2; ++cc) {
        const int iA = ib * IBLK + il + 2 * cc;   // h = 0
        const int iB = iA + 4;                    // h = 1
        qx[cc] = (v2f){qb[iA * 3 + 0], qb[iB * 3 + 0]};
        qy[cc] = (v2f){qb[iA * 3 + 1], qb[iB * 3 + 1]};
        qz[cc] = (v2f){qb[iA * 3 + 2], qb[iB * 3 + 2]};
        fx[cc] = (v2f)0.0f; fy[cc] = (v2f)0.0f; fz[cc] = (v2f)0.0f;
    }

    const float4* jq4 = (const float4*)(qb + (size_t)jc * JLEN * 3);

    // Diagonal chunk = ib>>1 -> lives in wave (ib>>6).
    if ((t >> 6) == (ib >> 6)) {
        chunk_loop<true >(jq4, qx, qy, qz, fx, fy, fz);
    } else {
        chunk_loop<false>(jq4, qx, qy, qz, fx, fy, fz);
    }

    // 12 partials/thread: slot = comp*4 + cc*2 + h; addr = jc*25 + slot*2 + il
    {
        float* r = &red[jc * RSTRIDE + il];
        r[0]  = fx[0].x;  r[2]  = fx[0].y;  r[4]  = fx[1].x;  r[6]  = fx[1].y;
        r[8]  = fy[0].x;  r[10] = fy[0].y;  r[12] = fy[1].x;  r[14] = fy[1].y;
        r[16] = fz[0].x;  r[18] = fz[0].y;  r[20] = fz[1].x;  r[22] = fz[1].y;
    }
    __syncthreads();

    // Stage 1: 384 threads; o = comp*8 + (il + 2cc + 4h), g = group of 16 chunks.
    if (t < 384) {
        const int o  = t >> 4;         // 0..23
        const int g  = t & 15;         // 0..15
        const int comp = o >> 3;
        const int rr   = o & 7;
        const int il2  = rr & 1;
        const int cc2  = (rr >> 1) & 1;
        const int h2   = rr >> 2;
        const int slot = comp * 4 + cc2 * 2 + h2;
        float s = 0.0f;
        #pragma unroll
        for (int qq = 0; qq < 16; ++qq) {
            s += red[(g * 16 + qq) * RSTRIDE + slot * 2 + il2];
        }
        red2[o * 16 + g] = s;
    }
    __syncthreads();

    // Stage 2: 24 threads -> one (comp, i-in-block) each; fuse dq = p/m.
    if (t < 24) {
        float s = 0.0f;
        #pragma unroll
        for (int g = 0; g < 16; ++g) s += red2[t * 16 + g];
        const int comp = t >> 3;
        const int ii   = t & 7;        // il + 2cc + 4h
        const size_t gi = (size_t)b * NPART + ib * IBLK + ii;
        dp[gi * 3 + comp] = s;
        dq[gi * 3 + comp] = p[gi * 3 + comp] / m[gi];   // exact IEEE div
    }
}

extern "C" void kernel_launch(void* const* d_in, const int* in_sizes, int n_in,
                              void* d_out, int out_size, void* d_ws, size_t ws_size,
                              hipStream_t stream) {
    const float* q = (const float*)d_in[0];
    const float* p = (const float*)d_in[1];
    const float* m = (const float*)d_in[2];
    // d_in[3] = t, unused by the reference outputs

    const int n_elem = BATCH * NPART * 3;   // 24576 per output tensor
    float* dq_out = (float*)d_out;          // first output: dq
    float* dp_out = (float*)d_out + n_elem; // second output: dp

    dim3 grid(NIB, BATCH);                  // 1024 blocks x 512 threads
    lj_fused<<<grid, NTHREADS, 0, stream>>>(q, p, m, dq_out, dp_out);
}

// Round 16
// 18.611 us; speedup vs baseline: 12.8101x; 11.2335x over previous
//
#include <hip/hip_runtime.h>

// Problem constants (match reference setup_inputs)
#define BATCH    2
#define NPART    4096
#define NTHREADS 512
#define ILANES   2                    // lane slots in i-dim
#define IBLK     8                    // i per block (4 per lane: 2 v2f chains)
#define JCH      (NTHREADS / ILANES)  // 256 j-chunks per block
#define JLEN     (NPART / JCH)        // 16 j per chunk
#define NIB      (NPART / IBLK)       // 512 i-blocks per batch
#define RSTRIDE  25                   // 24 partials + 1 pad

typedef float v2f __attribute__((ext_vector_type(2)));

// One (j, 2-i) interaction; v2f packs two i's, all by value/scalar-ref
// (NO arrays / pointer-passing anywhere -> SROA keeps everything in VGPRs;
// R14/R15's 240 MB scratch traffic came from memory-backed local arrays).
template <bool MASKED>
__device__ inline void lj_pair(float jx, float jy, float jz,
                               v2f qx, v2f qy, v2f qz,
                               v2f& fx, v2f& fy, v2f& fz) {
    const v2f dx = qx - (v2f)jx;
    const v2f dy = qy - (v2f)jy;
    const v2f dz = qz - (v2f)jz;
    v2f r2 = dx * dx;
    r2 = __builtin_elementwise_fma(dy, dy, r2);
    r2 = __builtin_elementwise_fma(dz, dz, r2);
    v2f inv;
    if (MASKED) {   // r2==0.0f exactly <=> i==j (reference's mask semantics)
        inv.x = (r2.x > 0.0f) ? __builtin_amdgcn_rcpf(r2.x) : 0.0f;
        inv.y = (r2.y > 0.0f) ? __builtin_amdgcn_rcpf(r2.y) : 0.0f;
    } else {
        inv.x = __builtin_amdgcn_rcpf(r2.x);
        inv.y = __builtin_amdgcn_rcpf(r2.y);
    }
    const v2f inv2 = inv * inv;
    const v2f s6 = inv2 * inv;                                      // sigma = 1
    const v2f c1 = __builtin_elementwise_fma((v2f)48.0f, s6, (v2f)(-24.0f));
    const v2f coeff = (inv * s6) * c1;     // 24*inv*s6*(2*s6-1)
    fx = __builtin_elementwise_fma(coeff, dx, fx);
    fy = __builtin_elementwise_fma(coeff, dy, fy);
    fz = __builtin_elementwise_fma(coeff, dz, fz);
}

// This lane's 16-j chunk: 12 float4 loads consumed in place; each j feeds
// both v2f chains (8 pairs). All operands are named scalars.
template <bool MASKED>
__device__ inline void chunk_loop(const float4* __restrict__ jq4,
                                  v2f qx0, v2f qy0, v2f qz0,
                                  v2f qx1, v2f qy1, v2f qz1,
                                  v2f& fx0, v2f& fy0, v2f& fz0,
                                  v2f& fx1, v2f& fy1, v2f& fz1) {
    #pragma unroll
    for (int it = 0; it < JLEN / 4; ++it) {
        const float4 A = jq4[3 * it + 0];   // x0 y0 z0 x1
        const float4 B = jq4[3 * it + 1];   // y1 z1 x2 y2
        const float4 C = jq4[3 * it + 2];   // z2 x3 y3 z3
        lj_pair<MASKED>(A.x, A.y, A.z, qx0, qy0, qz0, fx0, fy0, fz0);
        lj_pair<MASKED>(A.x, A.y, A.z, qx1, qy1, qz1, fx1, fy1, fz1);
        lj_pair<MASKED>(A.w, B.x, B.y, qx0, qy0, qz0, fx0, fy0, fz0);
        lj_pair<MASKED>(A.w, B.x, B.y, qx1, qy1, qz1, fx1, fy1, fz1);
        lj_pair<MASKED>(B.z, B.w, C.x, qx0, qy0, qz0, fx0, fy0, fz0);
        lj_pair<MASKED>(B.z, B.w, C.x, qx1, qy1, qz1, fx1, fy1, fz1);
        lj_pair<MASKED>(C.y, C.z, C.w, qx0, qy0, qz0, fx0, fy0, fz0);
        lj_pair<MASKED>(C.y, C.z, C.w, qx1, qy1, qz1, fx1, fy1, fz1);
    }
}

// Fully fused single dispatch. Block owns 8 i's (i = ib*8 + il + 2cc + 4h;
// chain cc in {0,1}, packed half h in {0,1}) x all 4096 j (256 chunks of 16).
// Two-stage LDS reduction. Only wave (ib>>6) can see the diagonal.
__global__ __launch_bounds__(NTHREADS, 4) void lj_fused(
        const float* __restrict__ q, const float* __restrict__ p,
        const float* __restrict__ m, float* __restrict__ dq,
        float* __restrict__ dp) {
    __shared__ float red[JCH * RSTRIDE];   // 25.6 KB
    __shared__ float red2[24 * 16];        // stage-1 partials

    const int ib = blockIdx.x;
    const int b  = blockIdx.y;
    const int t  = threadIdx.x;
    const int il = t & 1;
    const int jc = t >> 1;                 // 0..255

    const float* qb = q + (size_t)b * NPART * 3;

    const int iA0 = ib * IBLK + il;        // cc=0, h=0
    const int iB0 = iA0 + 4;               // cc=0, h=1
    const int iA1 = iA0 + 2;               // cc=1, h=0
    const int iB1 = iA1 + 4;               // cc=1, h=1
    const v2f qx0 = {qb[iA0 * 3 + 0], qb[iB0 * 3 + 0]};
    const v2f qy0 = {qb[iA0 * 3 + 1], qb[iB0 * 3 + 1]};
    const v2f qz0 = {qb[iA0 * 3 + 2], qb[iB0 * 3 + 2]};
    const v2f qx1 = {qb[iA1 * 3 + 0], qb[iB1 * 3 + 0]};
    const v2f qy1 = {qb[iA1 * 3 + 1], qb[iB1 * 3 + 1]};
    const v2f qz1 = {qb[iA1 * 3 + 2], qb[iB1 * 3 + 2]};

    v2f fx0 = (v2f)0.0f, fy0 = (v2f)0.0f, fz0 = (v2f)0.0f;
    v2f fx1 = (v2f)0.0f, fy1 = (v2f)0.0f, fz1 = (v2f)0.0f;

    const float4* jq4 = (const float4*)(qb + (size_t)jc * JLEN * 3);

    // Diagonal chunk = ib>>1 -> lives in wave (ib>>6).
    if ((t >> 6) == (ib >> 6)) {
        chunk_loop<true >(jq4, qx0, qy0, qz0, qx1, qy1, qz1,
                          fx0, fy0, fz0, fx1, fy1, fz1);
    } else {
        chunk_loop<false>(jq4, qx0, qy0, qz0, qx1, qy1, qz1,
                          fx0, fy0, fz0, fx1, fy1, fz1);
    }

    // 12 partials/thread: slot = comp*4 + cc*2 + h; addr = jc*25 + slot*2 + il
    {
        float* r = &red[jc * RSTRIDE + il];
        r[0]  = fx0.x;  r[2]  = fx0.y;  r[4]  = fx1.x;  r[6]  = fx1.y;
        r[8]  = fy0.x;  r[10] = fy0.y;  r[12] = fy1.x;  r[14] = fy1.y;
        r[16] = fz0.x;  r[18] = fz0.y;  r[20] = fz1.x;  r[22] = fz1.y;
    }
    __syncthreads();

    // Stage 1: 384 threads; o = comp*8 + (il + 2cc + 4h), g = group of 16 chunks.
    if (t < 384) {
        const int o  = t >> 4;         // 0..23
        const int g  = t & 15;         // 0..15
        const int comp = o >> 3;
        const int rr   = o & 7;
        const int il2  = rr & 1;
        const int cc2  = (rr >> 1) & 1;
        const int h2   = rr >> 2;
        const int slot = comp * 4 + cc2 * 2 + h2;
        float s = 0.0f;
        #pragma unroll
        for (int qq = 0; qq < 16; ++qq) {
            s += red[(g * 16 + qq) * RSTRIDE + slot * 2 + il2];
        }
        red2[o * 16 + g] = s;
    }
    __syncthreads();

    // Stage 2: 24 threads -> one (comp, i-in-block) each; fuse dq = p/m.
    if (t < 24) {
        float s = 0.0f;
        #pragma unroll
        for (int g = 0; g < 16; ++g) s += red2[t * 16 + g];
        const int comp = t >> 3;
        const int ii   = t & 7;        // il + 2cc + 4h
        const size_t gi = (size_t)b * NPART + ib * IBLK + ii;
        dp[gi * 3 + comp] = s;
        dq[gi * 3 + comp] = p[gi * 3 + comp] / m[gi];   // exact IEEE div
    }
}

extern "C" void kernel_launch(void* const* d_in, const int* in_sizes, int n_in,
                              void* d_out, int out_size, void* d_ws, size_t ws_size,
                              hipStream_t stream) {
    const float* q = (const float*)d_in[0];
    const float* p = (const float*)d_in[1];
    const float* m = (const float*)d_in[2];
    // d_in[3] = t, unused by the reference outputs

    const int n_elem = BATCH * NPART * 3;   // 24576 per output tensor
    float* dq_out = (float*)d_out;          // first output: dq
    float* dp_out = (float*)d_out + n_elem; // second output: dp

    dim3 grid(NIB, BATCH);                  // 1024 blocks x 512 threads
    lj_fused<<<grid, NTHREADS, 0, stream>>>(q, p, m, dq_out, dp_out);
}